// Round 8
// baseline (270.376 us; speedup 1.0000x reference)
//
#include <hip/hip_runtime.h>

typedef unsigned short ushort_t;
typedef __bf16 bf16x8 __attribute__((ext_vector_type(8)));
typedef float f32x4 __attribute__((ext_vector_type(4)));
typedef unsigned u32x4 __attribute__((ext_vector_type(4)));

// f32 -> bf16 bits, round-to-nearest-even (scalar path)
__device__ inline ushort_t f2bf(float f) {
  unsigned int u = __builtin_bit_cast(unsigned int, f);
  u += 0x7fff + ((u >> 16) & 1);
  return (ushort_t)(u >> 16);
}

// pack two f32 -> bf16x2 (RNE), b in high half — single HW instruction
__device__ inline unsigned pk_bf(float a, float b) {
  unsigned r;
  asm("v_cvt_pk_bf16_f32 %0, %1, %2" : "=v"(r) : "v"(a), "v"(b));
  return r;
}

// async global->LDS, 16B per lane; LDS dest = wave-uniform base + lane*16B
__device__ inline void async_ld16(const ushort_t* g, const ushort_t* l) {
  __builtin_amdgcn_global_load_lds(
      (const __attribute__((address_space(1))) void*)g,
      (__attribute__((address_space(3))) void*)l, 16, 0, 0);
}

// vmcnt(N) wait + workgroup barrier. IMM: 0x0F70|N (lgkm=15, exp=7 -> no wait)
template <int IMM>
__device__ inline void waitcnt_barrier() {
  asm volatile("" ::: "memory");
  __builtin_amdgcn_s_waitcnt(IMM);
  __builtin_amdgcn_s_barrier();
  asm volatile("" ::: "memory");
}

// one fused conversion kernel: x (1048576 f4) | Wa (786432 f4) | Wp (262144 f4)
__global__ void cvt_all(const float* __restrict__ x, const float* __restrict__ wa,
                        const float* __restrict__ wp, ushort_t* __restrict__ xb,
                        ushort_t* __restrict__ wab, ushort_t* __restrict__ wpb) {
  int i = blockIdx.x * 256 + threadIdx.x;
  const float* src;
  ushort_t* dst;
  int off;
  if (i < 1048576) { src = x; dst = xb; off = i; }
  else if (i < 1835008) { src = wa; dst = wab; off = i - 1048576; }
  else { src = wp; dst = wpb; off = i - 1835008; }
  float4 f = ((const float4*)src)[off];
  unsigned long long p = (unsigned long long)f2bf(f.x)
      | ((unsigned long long)f2bf(f.y) << 16)
      | ((unsigned long long)f2bf(f.z) << 32)
      | ((unsigned long long)f2bf(f.w) << 48);
  ((unsigned long long*)dst)[off] = p;
}

// C[m][n] = sum_k A[m][k]*B[n][k] + bias[n]; A:[M,K] bf16, B:[N,K] bf16.
// BK=32, TRIPLE-buffered LDS, depth-2 prefetch, manual vmcnt barriers.
template <int BM, int BN, int IM, int JN, int MODE, int TPB>
__global__ __launch_bounds__(TPB) void gemm_bt(
    const ushort_t* __restrict__ A, const ushort_t* __restrict__ B,
    const float* __restrict__ bias, float* __restrict__ Cf,
    ushort_t* __restrict__ Cb, ushort_t* __restrict__ vtb,
    int M, int N, int K, int ldc, float qscale) {
  constexpr int NWN = BN / (JN * 16);
  constexpr int NL = (BM + BN) * 32 / (TPB * 8);  // vmem loads/thread/stage
  constexpr int WIMM = 0x0F70 | NL;               // vmcnt(NL)
  __shared__ __align__(16) ushort_t As[3][BM * 32];
  __shared__ __align__(16) ushort_t Bs[3][BN * 32];
  const int tid = threadIdx.x;
  const int wave = tid >> 6, lane = tid & 63;
  const int quad = lane >> 4, l16 = lane & 15;
  const int wr = wave / NWN, wc = wave % NWN;
  const int wm = wr * IM * 16, wn = wc * JN * 16;
  const int m0 = blockIdx.y * BM, n0 = blockIdx.x * BN;
  const ushort_t* Ag = A + (size_t)m0 * K;
  const ushort_t* Bg = B + (size_t)n0 * K;
  const int slot = (quad ^ ((l16 >> 1) & 3)) * 8;
  f32x4 acc[IM][JN] = {};

  auto stage = [&](int kt, int bsel) {
    int k0 = kt * 32;
#pragma unroll
    for (int p = 0; p < BM * 4 / TPB; ++p) {
      int ci = p * TPB + tid;
      int row = ci >> 2, ch = (ci & 3) ^ ((ci >> 3) & 3);
      async_ld16(Ag + (size_t)row * K + k0 + ch * 8, As[bsel] + (p * TPB + wave * 64) * 8);
    }
#pragma unroll
    for (int p = 0; p < BN * 4 / TPB; ++p) {
      int ci = p * TPB + tid;
      int row = ci >> 2, ch = (ci & 3) ^ ((ci >> 3) & 3);
      async_ld16(Bg + (size_t)row * K + k0 + ch * 8, Bs[bsel] + (p * TPB + wave * 64) * 8);
    }
  };

  const int KT = K / 32;
  stage(0, 0);
  stage(1, 1);
  for (int kt = 0; kt < KT; ++kt) {
    waitcnt_barrier<WIMM>();  // stage(kt) landed; stage(kt+1) still in flight
    if (kt + 2 < KT) stage(kt + 2, (kt + 2) % 3);
    const ushort_t* Ac = As[kt % 3];
    const ushort_t* Bc = Bs[kt % 3];
    bf16x8 af[IM], bfr[JN];
#pragma unroll
    for (int i = 0; i < IM; ++i)
      af[i] = *(const bf16x8*)(Ac + (wm + i * 16 + l16) * 32 + slot);
#pragma unroll
    for (int j = 0; j < JN; ++j)
      bfr[j] = *(const bf16x8*)(Bc + (wn + j * 16 + l16) * 32 + slot);
#pragma unroll
    for (int i = 0; i < IM; ++i)
#pragma unroll
      for (int j = 0; j < JN; ++j)
        acc[i][j] = __builtin_amdgcn_mfma_f32_16x16x32_bf16(af[i], bfr[j], acc[i][j], 0, 0, 0);
  }

  if (MODE == 1 && n0 >= 2048) {
    // V third: write transposed packed to vtb[(b*16+h)*64+d][t]
#pragma unroll
    for (int j = 0; j < JN; ++j) {
      int col = n0 + wn + j * 16 + l16;
      int cv = col - 2048;
      float bv = bias[col];
      size_t rowbase = ((size_t)(cv >> 6)) * 64 + (cv & 63);  // (h*64+d) within batch
#pragma unroll
      for (int i = 0; i < IM; ++i) {
        int rowb = m0 + wm + i * 16 + quad * 4;
        int bb = rowb >> 11, t = rowb & 2047;
        uint2 pp;
        pp.x = pk_bf(acc[i][j][0] + bv, acc[i][j][1] + bv);
        pp.y = pk_bf(acc[i][j][2] + bv, acc[i][j][3] + bv);
        *(uint2*)(vtb + (((size_t)bb * 1024 + rowbase) * 2048 + t)) = pp;
      }
    }
    return;
  }
#pragma unroll
  for (int j = 0; j < JN; ++j) {
    int col = n0 + wn + j * 16 + l16;
    float bv = bias[col];
    float sc = (MODE == 1 && col < 1024) ? qscale : 1.0f;
#pragma unroll
    for (int i = 0; i < IM; ++i)
#pragma unroll
      for (int r = 0; r < 4; ++r) {
        int row = m0 + wm + i * 16 + quad * 4 + r;
        float v = (acc[i][j][r] + bv) * sc;
        if (MODE == 1)
          Cb[(size_t)row * ldc + col] = f2bf(v);
        else
          Cf[(size_t)row * ldc + col] = v;
      }
  }
}

// Transposed flash attention, causal, exp2 basis, static max.
// r18 = r17 (LDS-free, barrier-free) with the K-fragment addressing bug
// fixed: d-offset is quad*8 ELEMENTS within a 32-wide k-slice (ks*32), same
// as the Q fragment — r17 had quad*16/ks*64 (bytes-vs-elements slip), which
// read the NEXT HEAD's K for quad>=2 / ks=1 (absmax 2.09).
// Fragment derivation (verified against the LDS version it replaces):
//   kf[jj][ks][e] = qk[(bT+t*64+kappa(jj,l16))*2048 +1024+ h*64 + ks*32+quad*8+e]
//   vf[jj][ks][e] = vt[(bh*64+jj*16+l16)*2048 + t*64 + quad*16 + ks*8 + e]
// All 8 waves read the SAME 8KB K-tile + 8KB V-tile -> lead wave takes the
// L2 miss, the rest hit L1 (32KB holds both). Per-XCD working set ~1MB fits
// the 4MB L2. Waves FREE-RUN (zero sync); kf latency hides under co-resident
// waves' softmax/PV. VGPR<=128 (launch_bounds 512,4) keeps 2 blocks/CU.
// Kappa row permutation (P stays in registers), ones-MFMA l-sum, uniform
// snake split, fence-free combine all kept.
// Work layout (per bh, w = blockIdx.x in [0,16)):
//   even w: q-tile j=15-w/2, key-tiles [0,17)          -> partial slot 0
//   odd  w: q-tile j0=15-w/2, key-tiles [17,2*j0+2)    -> partial slot 1
//           then q-tile j1=w/2, key-tiles [0,2*j1+2)   -> final write
__global__ __launch_bounds__(512, 4) void flash14(
    const ushort_t* __restrict__ qk, const ushort_t* __restrict__ vt,
    ushort_t* __restrict__ y, float* __restrict__ pO, float* __restrict__ pl) {
  const int tid = threadIdx.x, wave = tid >> 6, lane = tid & 63;
  const int quad = lane >> 4, l16 = lane & 15;
  const int w = blockIdx.x, bh = blockIdx.y;
  const int b = bh >> 4, h = bh & 15;
  const int bT = b * 2048;
  const int nseg = (w & 1) ? 2 : 1;
  const int krow0 = 16 * (l16 >> 2) + (l16 & 3);  // kappa(0, l16)
  // all-ones A fragment (bf16 1.0 = 0x3F80) for the l row-sum MFMA
  u32x4 onesw;
  onesw[0] = 0x3F803F80u; onesw[1] = 0x3F803F80u;
  onesw[2] = 0x3F803F80u; onesw[3] = 0x3F803F80u;
  const bf16x8 ones = __builtin_bit_cast(bf16x8, onesw);

  // per-lane global bases (element units)
  const ushort_t* Kl = qk + (size_t)(bT + krow0) * 2048 + 1024 + h * 64 + quad * 8;
  const ushort_t* Vl = vt + (size_t)(bh * 64 + l16) * 2048 + quad * 16;

  for (int seg = 0; seg < nseg; ++seg) {
    int j, tbeg, tend, isfin;
    if (w & 1) {
      if (seg == 0) { j = 15 - (w >> 1); tbeg = 17; tend = 2 * j + 2; isfin = 0; }
      else          { j = w >> 1;        tbeg = 0;  tend = 2 * j + 2; isfin = 1; }
    } else          { j = 15 - (w >> 1); tbeg = 0;  tend = 17;        isfin = 0; }
    const int qt0 = j * 128;             // tile's first q row (within batch)
    const int qw = qt0 + wave * 16;      // this wave's q rows
    const int qloc = qw + l16;

    // Q B-fragment direct from global: rows qw+l16
    bf16x8 qf[2];
    {
      const ushort_t* qrow = qk + (size_t)(bT + qloc) * 2048 + h * 64 + quad * 8;
      qf[0] = *(const bf16x8*)(qrow);
      qf[1] = *(const bf16x8*)(qrow + 32);
    }

    f32x4 o[4] = {};
    f32x4 lacc = {};

    for (int t = tbeg; t < tend; ++t) {
      const ushort_t* Kt = Kl + (size_t)t * 131072;  // t*64 rows * 2048
      const ushort_t* Vt = Vl + t * 64;
      // K fragments in kappa row order, straight from global (L1-shared
      // across the block's 8 waves). row kappa(jj,l16)=krow0+4jj; d-offset
      // within head = ks*32 + quad*8 (+e) — element units.
      bf16x8 kf[4][2];
#pragma unroll
      for (int jj = 0; jj < 4; ++jj)
#pragma unroll
        for (int ks = 0; ks < 2; ++ks)
          kf[jj][ks] = *(const bf16x8*)(Kt + (size_t)jj * 8192 + ks * 32);
      // S^T: 8 MFMAs, 4 independent chains of 2
      f32x4 sr[4] = {};
#pragma unroll
      for (int ks = 0; ks < 2; ++ks)
#pragma unroll
        for (int jj = 0; jj < 4; ++jj)
          sr[jj] = __builtin_amdgcn_mfma_f32_16x16x32_bf16(kf[jj][ks], qf[ks], sr[jj], 0, 0, 0);
      // V fragments issued now so their latency hides under softmax
      bf16x8 vf[4][2];
#pragma unroll
      for (int jj = 0; jj < 4; ++jj)
#pragma unroll
        for (int ks = 0; ks < 2; ++ks)
          vf[jj][ks] = *(const bf16x8*)(Vt + (size_t)jj * 32768 + ks * 8);
      if (t >= 2 * j) {  // diagonal tile: elementwise causal mask (kappa keys)
#pragma unroll
        for (int jj = 0; jj < 4; ++jj)
#pragma unroll
          for (int r = 0; r < 4; ++r)
            if (t * 64 + quad * 16 + jj * 4 + r > qloc) sr[jj][r] = -1e30f;
      }
      // static-max softmax, fully in-register
#pragma unroll
      for (int jj = 0; jj < 4; ++jj)
#pragma unroll
        for (int r = 0; r < 4; ++r)
          sr[jj][r] = exp2f(sr[jj][r]);
      // P^T B-frags are lane-local under kappa: keys 8ks+16quad+0..7
      bf16x8 pf[2];
#pragma unroll
      for (int ks = 0; ks < 2; ++ks) {
        u32x4 wd;
        wd[0] = pk_bf(sr[2 * ks][0], sr[2 * ks][1]);
        wd[1] = pk_bf(sr[2 * ks][2], sr[2 * ks][3]);
        wd[2] = pk_bf(sr[2 * ks + 1][0], sr[2 * ks + 1][1]);
        wd[3] = pk_bf(sr[2 * ks + 1][2], sr[2 * ks + 1][3]);
        pf[ks] = __builtin_bit_cast(bf16x8, wd);
      }
      // l row-sum on the matrix pipe: lacc[q] += sum_k P[k][q]
      lacc = __builtin_amdgcn_mfma_f32_16x16x32_bf16(ones, pf[0], lacc, 0, 0, 0);
      lacc = __builtin_amdgcn_mfma_f32_16x16x32_bf16(ones, pf[1], lacc, 0, 0, 0);
      // O^T += V^T * P^T
#pragma unroll
      for (int ks = 0; ks < 2; ++ks)
#pragma unroll
        for (int jj = 0; jj < 4; ++jj)
          o[jj] = __builtin_amdgcn_mfma_f32_16x16x32_bf16(vf[jj][ks], pf[ks], o[jj], 0, 0, 0);
    }

    // epilogue: l is already fully reduced (every reg/quad holds the same sum)
    float l = lacc[0];
    const int rowloc = wave * 16 + l16;  // 0..127 within the q-tile

    if (isfin) {
      float inv = 1.f / l;
      size_t row = (size_t)(bT + qt0 + rowloc);
#pragma unroll
      for (int jj = 0; jj < 4; ++jj) {
        uint2 pp;
        pp.x = pk_bf(o[jj][0] * inv, o[jj][1] * inv);
        pp.y = pk_bf(o[jj][2] * inv, o[jj][3] * inv);
        *(uint2*)(y + row * 1024 + h * 64 + jj * 16 + quad * 4) = pp;
      }
    } else {
      // plain partial stores; visibility guaranteed at kernel boundary
      const int tile = bh * 8 + (j - 8);  // 0..255
      const int slot = w & 1;
      float* po = pO + ((size_t)(tile * 2 + slot)) * 8192;
#pragma unroll
      for (int jj = 0; jj < 4; ++jj)
        *(f32x4*)(po + rowloc * 64 + jj * 16 + quad * 4) = o[jj];
      if (quad == 0) pl[(tile * 2 + slot) * 128 + rowloc] = l;
    }
  }
}

// combine split-tile partials: y = (O0 + O1) / (l0 + l1), bf16.
// 256 tiles (bh in [0,32) x j in [8,16)), 128 rows x 64 cols each.
__global__ __launch_bounds__(256) void combine(
    const float* __restrict__ pO, const float* __restrict__ pl,
    ushort_t* __restrict__ y) {
  const int tile = blockIdx.x;          // 0..255
  const int bh = tile >> 3, j = (tile & 7) + 8;
  const int b = bh >> 4, h = bh & 15;
  const int row = threadIdx.x >> 1;     // 0..127
  const int c0 = (threadIdx.x & 1) * 32;
  const float* p0 = pO + (size_t)(tile * 2 + 0) * 8192 + row * 64 + c0;
  const float* p1 = pO + (size_t)(tile * 2 + 1) * 8192 + row * 64 + c0;
  const float inv = 1.f / (pl[(tile * 2) * 128 + row] + pl[(tile * 2 + 1) * 128 + row]);
  ushort_t* yr = y + (size_t)(b * 2048 + j * 128 + row) * 1024 + h * 64 + c0;
#pragma unroll
  for (int c = 0; c < 8; ++c) {
    f32x4 a = *(const f32x4*)(p0 + c * 4);
    f32x4 bb = *(const f32x4*)(p1 + c * 4);
    uint2 pp;
    pp.x = pk_bf((a[0] + bb[0]) * inv, (a[1] + bb[1]) * inv);
    pp.y = pk_bf((a[2] + bb[2]) * inv, (a[3] + bb[3]) * inv);
    *(uint2*)(yr + c * 4) = pp;
  }
}

extern "C" void kernel_launch(void* const* d_in, const int* in_sizes, int n_in,
                              void* d_out, int out_size, void* d_ws, size_t ws_size,
                              hipStream_t stream) {
  const float* x  = (const float*)d_in[0];
  const float* Wa = (const float*)d_in[1];
  const float* ba = (const float*)d_in[2];
  const float* Wp = (const float*)d_in[3];
  const float* bp = (const float*)d_in[4];
  float* out = (float*)d_out;
  char* ws = (char*)d_ws;
  // ws: xb 8.39M | Wab 6.29M | Wpb 2.10M | qk 16.78M | yb 8.39M | vt 8.39M
  // | (64M) pO 16.78M f32 | (80M) pl 256K   (ws = 256MiB)
  ushort_t* xb  = (ushort_t*)(ws);
  ushort_t* Wab = (ushort_t*)(ws + 8388608);
  ushort_t* Wpb = (ushort_t*)(ws + 14680064);
  ushort_t* qkb = (ushort_t*)(ws + 16777216);
  ushort_t* yb  = (ushort_t*)(ws + 33554432);
  ushort_t* vtb = (ushort_t*)(ws + 41943040);
  float*    pO  = (float*)(ws + 67108864);
  float*    pl  = (float*)(ws + 83886080);

  cvt_all<<<8192, 256, 0, stream>>>(x, Wa, Wp, xb, Wab, Wpb);
  // qkv = x @ W_attn^T + b_attn; Q scaled by 0.125*log2(e); V written transposed
  gemm_bt<128, 128, 4, 2, 1, 512><<<dim3(24, 32), 512, 0, stream>>>(
      xb, Wab, ba, nullptr, qkb, vtb, 4096, 3072, 1024, 2048, 0.18033688011112042f);
  // flash attention (512 uniform blocks, 17 key-tiles each, LDS-free,
  // barrier-free; K/V through L1/L2)
  flash14<<<dim3(16, 32), 512, 0, stream>>>(qkb, vtb, yb, pO, pl);
  // combine split-tile partials (kernel boundary = the sync)
  combine<<<256, 256, 0, stream>>>(pO, pl, yb);
  // out = yb @ W_proj^T + b_proj  [4096,1024] f32
  gemm_bt<128, 128, 4, 2, 0, 512><<<dim3(8, 32), 512, 0, stream>>>(
      yb, Wpb, bp, out, nullptr, nullptr, 4096, 1024, 1024, 1024, 1.0f);
}

// Round 9
// 179.455 us; speedup vs baseline: 1.5066x; 1.5066x over previous
//
#include <hip/hip_runtime.h>

typedef unsigned short ushort_t;
typedef __bf16 bf16x8 __attribute__((ext_vector_type(8)));
typedef float f32x4 __attribute__((ext_vector_type(4)));
typedef unsigned u32x4 __attribute__((ext_vector_type(4)));

// f32 -> bf16 bits, round-to-nearest-even (scalar path)
__device__ inline ushort_t f2bf(float f) {
  unsigned int u = __builtin_bit_cast(unsigned int, f);
  u += 0x7fff + ((u >> 16) & 1);
  return (ushort_t)(u >> 16);
}

// pack two f32 -> bf16x2 (RNE), b in high half — single HW instruction
__device__ inline unsigned pk_bf(float a, float b) {
  unsigned r;
  asm("v_cvt_pk_bf16_f32 %0, %1, %2" : "=v"(r) : "v"(a), "v"(b));
  return r;
}

// async global->LDS, 16B per lane; LDS dest = wave-uniform base + lane*16B
__device__ inline void async_ld16(const ushort_t* g, const ushort_t* l) {
  __builtin_amdgcn_global_load_lds(
      (const __attribute__((address_space(1))) void*)g,
      (__attribute__((address_space(3))) void*)l, 16, 0, 0);
}

// vmcnt(N) wait + workgroup barrier. IMM: 0x0F70|N (lgkm=15, exp=7 -> no wait)
template <int IMM>
__device__ inline void waitcnt_barrier() {
  asm volatile("" ::: "memory");
  __builtin_amdgcn_s_waitcnt(IMM);
  __builtin_amdgcn_s_barrier();
  asm volatile("" ::: "memory");
}

// one fused conversion kernel: x (1048576 f4) | Wa (786432 f4) | Wp (262144 f4)
__global__ void cvt_all(const float* __restrict__ x, const float* __restrict__ wa,
                        const float* __restrict__ wp, ushort_t* __restrict__ xb,
                        ushort_t* __restrict__ wab, ushort_t* __restrict__ wpb) {
  int i = blockIdx.x * 256 + threadIdx.x;
  const float* src;
  ushort_t* dst;
  int off;
  if (i < 1048576) { src = x; dst = xb; off = i; }
  else if (i < 1835008) { src = wa; dst = wab; off = i - 1048576; }
  else { src = wp; dst = wpb; off = i - 1835008; }
  float4 f = ((const float4*)src)[off];
  unsigned long long p = (unsigned long long)f2bf(f.x)
      | ((unsigned long long)f2bf(f.y) << 16)
      | ((unsigned long long)f2bf(f.z) << 32)
      | ((unsigned long long)f2bf(f.w) << 48);
  ((unsigned long long*)dst)[off] = p;
}

// C[m][n] = sum_k A[m][k]*B[n][k] + bias[n]; A:[M,K] bf16, B:[N,K] bf16.
// BK=32, TRIPLE-buffered LDS, depth-2 prefetch, manual vmcnt barriers.
template <int BM, int BN, int IM, int JN, int MODE, int TPB>
__global__ __launch_bounds__(TPB) void gemm_bt(
    const ushort_t* __restrict__ A, const ushort_t* __restrict__ B,
    const float* __restrict__ bias, float* __restrict__ Cf,
    ushort_t* __restrict__ Cb, ushort_t* __restrict__ vtb,
    int M, int N, int K, int ldc, float qscale) {
  constexpr int NWN = BN / (JN * 16);
  constexpr int NL = (BM + BN) * 32 / (TPB * 8);  // vmem loads/thread/stage
  constexpr int WIMM = 0x0F70 | NL;               // vmcnt(NL)
  __shared__ __align__(16) ushort_t As[3][BM * 32];
  __shared__ __align__(16) ushort_t Bs[3][BN * 32];
  const int tid = threadIdx.x;
  const int wave = tid >> 6, lane = tid & 63;
  const int quad = lane >> 4, l16 = lane & 15;
  const int wr = wave / NWN, wc = wave % NWN;
  const int wm = wr * IM * 16, wn = wc * JN * 16;
  const int m0 = blockIdx.y * BM, n0 = blockIdx.x * BN;
  const ushort_t* Ag = A + (size_t)m0 * K;
  const ushort_t* Bg = B + (size_t)n0 * K;
  const int slot = (quad ^ ((l16 >> 1) & 3)) * 8;
  f32x4 acc[IM][JN] = {};

  auto stage = [&](int kt, int bsel) {
    int k0 = kt * 32;
#pragma unroll
    for (int p = 0; p < BM * 4 / TPB; ++p) {
      int ci = p * TPB + tid;
      int row = ci >> 2, ch = (ci & 3) ^ ((ci >> 3) & 3);
      async_ld16(Ag + (size_t)row * K + k0 + ch * 8, As[bsel] + (p * TPB + wave * 64) * 8);
    }
#pragma unroll
    for (int p = 0; p < BN * 4 / TPB; ++p) {
      int ci = p * TPB + tid;
      int row = ci >> 2, ch = (ci & 3) ^ ((ci >> 3) & 3);
      async_ld16(Bg + (size_t)row * K + k0 + ch * 8, Bs[bsel] + (p * TPB + wave * 64) * 8);
    }
  };

  const int KT = K / 32;
  stage(0, 0);
  stage(1, 1);
  for (int kt = 0; kt < KT; ++kt) {
    waitcnt_barrier<WIMM>();  // stage(kt) landed; stage(kt+1) still in flight
    if (kt + 2 < KT) stage(kt + 2, (kt + 2) % 3);
    const ushort_t* Ac = As[kt % 3];
    const ushort_t* Bc = Bs[kt % 3];
    bf16x8 af[IM], bfr[JN];
#pragma unroll
    for (int i = 0; i < IM; ++i)
      af[i] = *(const bf16x8*)(Ac + (wm + i * 16 + l16) * 32 + slot);
#pragma unroll
    for (int j = 0; j < JN; ++j)
      bfr[j] = *(const bf16x8*)(Bc + (wn + j * 16 + l16) * 32 + slot);
#pragma unroll
    for (int i = 0; i < IM; ++i)
#pragma unroll
      for (int j = 0; j < JN; ++j)
        acc[i][j] = __builtin_amdgcn_mfma_f32_16x16x32_bf16(af[i], bfr[j], acc[i][j], 0, 0, 0);
  }

  if (MODE == 1 && n0 >= 2048) {
    // V third: write transposed packed to vtb[(b*16+h)*64+d][t]
#pragma unroll
    for (int j = 0; j < JN; ++j) {
      int col = n0 + wn + j * 16 + l16;
      int cv = col - 2048;
      float bv = bias[col];
      size_t rowbase = ((size_t)(cv >> 6)) * 64 + (cv & 63);  // (h*64+d) within batch
#pragma unroll
      for (int i = 0; i < IM; ++i) {
        int rowb = m0 + wm + i * 16 + quad * 4;
        int bb = rowb >> 11, t = rowb & 2047;
        uint2 pp;
        pp.x = pk_bf(acc[i][j][0] + bv, acc[i][j][1] + bv);
        pp.y = pk_bf(acc[i][j][2] + bv, acc[i][j][3] + bv);
        *(uint2*)(vtb + (((size_t)bb * 1024 + rowbase) * 2048 + t)) = pp;
      }
    }
    return;
  }
#pragma unroll
  for (int j = 0; j < JN; ++j) {
    int col = n0 + wn + j * 16 + l16;
    float bv = bias[col];
    float sc = (MODE == 1 && col < 1024) ? qscale : 1.0f;
#pragma unroll
    for (int i = 0; i < IM; ++i)
#pragma unroll
      for (int r = 0; r < 4; ++r) {
        int row = m0 + wm + i * 16 + quad * 4 + r;
        float v = (acc[i][j][r] + bv) * sc;
        if (MODE == 1)
          Cb[(size_t)row * ldc + col] = f2bf(v);
        else
          Cf[(size_t)row * ldc + col] = v;
      }
  }
}

// Transposed flash attention, causal, exp2 basis, static max.
// r19 = r16's flash12 verbatim (proven 37 µs / passing). r17/r18's LDS-free
// variant is REFUTED: per-wave segment count (not bytes/lane) governs
// coalescing — direct kf/vf reads scatter each wave across 16 rows 4KB
// apart => ~16 transactions/load, flash 37->132 µs. LDS staging stays.
// Work layout (per bh, w = blockIdx.x in [0,16)):
//   even w: q-tile j=15-w/2, key-tiles [0,17)          -> partial slot 0
//   odd  w: q-tile j0=15-w/2, key-tiles [17,2*j0+2)    -> partial slot 1
//           then q-tile j1=w/2, key-tiles [0,2*j1+2)   -> final write
// Every block = exactly 17 key-tiles = 9 supers; static-max softmax =>
// partials combine by pure addition of (O, l) in the separate combine
// kernel (kernel boundary = the only fence-free cross-block sync).
// Kappa-permuted K rows keep P in registers; v_cvt_pk_bf16_f32 packs;
// l row-sum via ones-MFMA on the matrix pipe.
__global__ __launch_bounds__(512, 2) void flash12(
    const ushort_t* __restrict__ qk, const ushort_t* __restrict__ vt,
    ushort_t* __restrict__ y, float* __restrict__ pO, float* __restrict__ pl) {
  __shared__ __align__(16) ushort_t Kb[2][2][4096];
  __shared__ __align__(16) ushort_t Vb[2][2][4096];
  const int tid = threadIdx.x, wave = tid >> 6, lane = tid & 63;
  const int quad = lane >> 4, l16 = lane & 15;
  const int r7 = l16 & 7;
  // f(kappa(jj,l16)) = kappa bits {0,1,4} — jj-independent
  const int fK = (l16 & 3) | (((l16 >> 2) & 1) << 2);
  // kappa base row (elements): kappa(jj,l16) = 16*(l16>>2) + (l16&3) + 4*jj
  const int kbase = (16 * (l16 >> 2) + (l16 & 3)) * 64;
  const int w = blockIdx.x, bh = blockIdx.y;
  const int b = bh >> 4, h = bh & 15;
  const int bT = b * 2048;
  const int nseg = (w & 1) ? 2 : 1;
  // all-ones A fragment (bf16 1.0 = 0x3F80) for the l row-sum MFMA
  u32x4 onesw;
  onesw[0] = 0x3F803F80u; onesw[1] = 0x3F803F80u;
  onesw[2] = 0x3F803F80u; onesw[3] = 0x3F803F80u;
  const bf16x8 ones = __builtin_bit_cast(bf16x8, onesw);

  // stage one 64-key tile t into (bsel, u)
  auto stage1 = [&](int t, int bsel, int u) {
    int k0 = t * 64;
    int row = tid >> 3;
    int chk = (tid & 7) ^ ((row & 3) | (((row >> 4) & 1) << 2));  // f(key)
    int chv = (tid & 7) ^ (row & 7);                              // d&7
    async_ld16(qk + (size_t)(bT + k0 + row) * 2048 + 1024 + h * 64 + chk * 8,
               Kb[bsel][u] + wave * 512);
    async_ld16(vt + (size_t)(bh * 64 + row) * 2048 + k0 + chv * 8,
               Vb[bsel][u] + wave * 512);
  };

  for (int seg = 0; seg < nseg; ++seg) {
    int j, tbeg, tend, isfin;
    if (w & 1) {
      if (seg == 0) { j = 15 - (w >> 1); tbeg = 17; tend = 2 * j + 2; isfin = 0; }
      else          { j = w >> 1;        tbeg = 0;  tend = 2 * j + 2; isfin = 1; }
    } else          { j = 15 - (w >> 1); tbeg = 0;  tend = 17;        isfin = 0; }
    const int qt0 = j * 128;             // tile's first q row (within batch)
    const int qw = qt0 + wave * 16;      // this wave's q rows
    const int qloc = qw + l16;

    // Q B-fragment direct from global: rows qw+l16
    bf16x8 qf[2];
    {
      const ushort_t* qrow = qk + (size_t)(bT + qloc) * 2048 + h * 64 + quad * 8;
      qf[0] = *(const bf16x8*)(qrow);
      qf[1] = *(const bf16x8*)(qrow + 32);
    }

    auto stageS = [&](int s, int bsel) {
      int t0 = tbeg + 2 * s;
      stage1(t0, bsel, 0);
      if (t0 + 1 < tend) stage1(t0 + 1, bsel, 1);
    };

    f32x4 o[4] = {};
    f32x4 lacc = {};
    const int NSs = (tend - tbeg + 1) >> 1;  // supers (1 or 2 tiles each)

    // WAR guard: seg1 restages LDS that slow waves may still read (seg0 tail)
    if (seg) __syncthreads();
    stageS(0, 0);
    for (int s = 0; s < NSs; ++s) {
      const int cur = s & 1;
      // stage(s) landed (in flight one full body, except s=0); all waves past
      // reading buffer cur^1 -> safe to re-stage it.
      waitcnt_barrier<0x0F70>();
      if (s + 1 < NSs) stageS(s + 1, cur ^ 1);
      __builtin_amdgcn_s_setprio(1);
      const int t0 = tbeg + 2 * s;
#pragma unroll
      for (int u = 0; u < 2; ++u) {
        if (u == 1 && t0 + 1 >= tend) break;
        const int kt = t0 + u;
        const ushort_t* Kc = Kb[cur][u];
        const ushort_t* Vc = Vb[cur][u];
        // K fragments in kappa row order: row kappa(jj,l16), d-chunk ks*4+quad
        bf16x8 kf[4][2];
#pragma unroll
        for (int jj = 0; jj < 4; ++jj)
#pragma unroll
          for (int ks = 0; ks < 2; ++ks)
            kf[jj][ks] = *(const bf16x8*)(Kc + kbase + jj * 256 + (((ks * 4 + quad) ^ fK) * 8));
        // S^T: 8 MFMAs, 4 independent chains of 2
        f32x4 sr[4] = {};
#pragma unroll
        for (int ks = 0; ks < 2; ++ks)
#pragma unroll
          for (int jj = 0; jj < 4; ++jj)
            sr[jj] = __builtin_amdgcn_mfma_f32_16x16x32_bf16(kf[jj][ks], qf[ks], sr[jj], 0, 0, 0);
        if (kt >= 2 * j) {  // diagonal tile: elementwise causal mask (kappa keys)
#pragma unroll
          for (int jj = 0; jj < 4; ++jj)
#pragma unroll
            for (int r = 0; r < 4; ++r)
              if (kt * 64 + quad * 16 + jj * 4 + r > qloc) sr[jj][r] = -1e30f;
        }
        // static-max softmax, fully in-register
#pragma unroll
        for (int jj = 0; jj < 4; ++jj)
#pragma unroll
          for (int r = 0; r < 4; ++r)
            sr[jj][r] = exp2f(sr[jj][r]);
        // P^T B-frags are lane-local under kappa: keys 8ks+16quad+0..7
        bf16x8 pf[2];
#pragma unroll
        for (int ks = 0; ks < 2; ++ks) {
          u32x4 wd;
          wd[0] = pk_bf(sr[2 * ks][0], sr[2 * ks][1]);
          wd[1] = pk_bf(sr[2 * ks][2], sr[2 * ks][3]);
          wd[2] = pk_bf(sr[2 * ks + 1][0], sr[2 * ks + 1][1]);
          wd[3] = pk_bf(sr[2 * ks + 1][2], sr[2 * ks + 1][3]);
          pf[ks] = __builtin_bit_cast(bf16x8, wd);
        }
        // l row-sum on the matrix pipe: lacc[q] += sum_k P[k][q]
        lacc = __builtin_amdgcn_mfma_f32_16x16x32_bf16(ones, pf[0], lacc, 0, 0, 0);
        lacc = __builtin_amdgcn_mfma_f32_16x16x32_bf16(ones, pf[1], lacc, 0, 0, 0);
        // O^T += V^T * P^T; V frag = keys 8ks+16quad+0..7 (chunk ks+2quad)
#pragma unroll
        for (int ks = 0; ks < 2; ++ks)
#pragma unroll
          for (int jj = 0; jj < 4; ++jj) {
            bf16x8 vf = *(const bf16x8*)(Vc + (jj * 16 + l16) * 64 + (((ks + 2 * quad) ^ r7) * 8));
            o[jj] = __builtin_amdgcn_mfma_f32_16x16x32_bf16(vf, pf[ks], o[jj], 0, 0, 0);
          }
      }
      __builtin_amdgcn_s_setprio(0);
    }

    // epilogue: l is already fully reduced (every reg/quad holds the same sum)
    float l = lacc[0];
    const int rowloc = wave * 16 + l16;  // 0..127 within the q-tile

    if (isfin) {
      float inv = 1.f / l;
      size_t row = (size_t)(bT + qt0 + rowloc);
#pragma unroll
      for (int jj = 0; jj < 4; ++jj) {
        uint2 pp;
        pp.x = pk_bf(o[jj][0] * inv, o[jj][1] * inv);
        pp.y = pk_bf(o[jj][2] * inv, o[jj][3] * inv);
        *(uint2*)(y + row * 1024 + h * 64 + jj * 16 + quad * 4) = pp;
      }
    } else {
      // plain partial stores; visibility guaranteed at kernel boundary
      const int tile = bh * 8 + (j - 8);  // 0..255
      const int slot = w & 1;
      float* po = pO + ((size_t)(tile * 2 + slot)) * 8192;
#pragma unroll
      for (int jj = 0; jj < 4; ++jj)
        *(f32x4*)(po + rowloc * 64 + jj * 16 + quad * 4) = o[jj];
      if (quad == 0) pl[(tile * 2 + slot) * 128 + rowloc] = l;
    }
  }
}

// combine split-tile partials: y = (O0 + O1) / (l0 + l1), bf16.
// r19: 512 blocks (2 per tile, 64 rows each) — the 256-block version was
// 1 block/CU latency-bound at 6 µs vs ~3 µs traffic roofline.
__global__ __launch_bounds__(256) void combine(
    const float* __restrict__ pO, const float* __restrict__ pl,
    ushort_t* __restrict__ y) {
  const int tile = blockIdx.x >> 1;                    // 0..255
  const int rbase = (blockIdx.x & 1) * 64;             // row half
  const int bh = tile >> 3, j = (tile & 7) + 8;
  const int b = bh >> 4, h = bh & 15;
  const int row = rbase + (threadIdx.x >> 2);          // 64 rows, 4 thr/row
  const int c0 = (threadIdx.x & 3) * 16;               // 16 cols/thread
  const float* p0 = pO + (size_t)(tile * 2 + 0) * 8192 + row * 64 + c0;
  const float* p1 = pO + (size_t)(tile * 2 + 1) * 8192 + row * 64 + c0;
  const float inv = 1.f / (pl[(tile * 2) * 128 + row] + pl[(tile * 2 + 1) * 128 + row]);
  ushort_t* yr = y + (size_t)(b * 2048 + j * 128 + row) * 1024 + h * 64 + c0;
#pragma unroll
  for (int c = 0; c < 4; ++c) {
    f32x4 a = *(const f32x4*)(p0 + c * 4);
    f32x4 bb = *(const f32x4*)(p1 + c * 4);
    uint2 pp;
    pp.x = pk_bf((a[0] + bb[0]) * inv, (a[1] + bb[1]) * inv);
    pp.y = pk_bf((a[2] + bb[2]) * inv, (a[3] + bb[3]) * inv);
    *(uint2*)(yr + c * 4) = pp;
  }
}

extern "C" void kernel_launch(void* const* d_in, const int* in_sizes, int n_in,
                              void* d_out, int out_size, void* d_ws, size_t ws_size,
                              hipStream_t stream) {
  const float* x  = (const float*)d_in[0];
  const float* Wa = (const float*)d_in[1];
  const float* ba = (const float*)d_in[2];
  const float* Wp = (const float*)d_in[3];
  const float* bp = (const float*)d_in[4];
  float* out = (float*)d_out;
  char* ws = (char*)d_ws;
  // ws: xb 8.39M | Wab 6.29M | Wpb 2.10M | qk 16.78M | yb 8.39M | vt 8.39M
  // | (64M) pO 16.78M f32 | (80M) pl 256K   (ws = 256MiB)
  ushort_t* xb  = (ushort_t*)(ws);
  ushort_t* Wab = (ushort_t*)(ws + 8388608);
  ushort_t* Wpb = (ushort_t*)(ws + 14680064);
  ushort_t* qkb = (ushort_t*)(ws + 16777216);
  ushort_t* yb  = (ushort_t*)(ws + 33554432);
  ushort_t* vtb = (ushort_t*)(ws + 41943040);
  float*    pO  = (float*)(ws + 67108864);
  float*    pl  = (float*)(ws + 83886080);

  cvt_all<<<8192, 256, 0, stream>>>(x, Wa, Wp, xb, Wab, Wpb);
  // qkv = x @ W_attn^T + b_attn; Q scaled by 0.125*log2(e); V written transposed
  gemm_bt<128, 128, 4, 2, 1, 512><<<dim3(24, 32), 512, 0, stream>>>(
      xb, Wab, ba, nullptr, qkb, vtb, 4096, 3072, 1024, 2048, 0.18033688011112042f);
  // flash attention (512 uniform blocks, 17 key-tiles each, fence-free)
  flash12<<<dim3(16, 32), 512, 0, stream>>>(qkb, vtb, yb, pO, pl);
  // combine split-tile partials (kernel boundary = the sync; 512 blocks)
  combine<<<512, 256, 0, stream>>>(pO, pl, yb);
  // out = yb @ W_proj^T + b_proj  [4096,1024] f32 — 64x128 tile, 512 blocks
  // (prior 128x128 grid was 256 blocks = 1/CU, no inter-block overlap, 716 TF)
  gemm_bt<64, 128, 4, 2, 0, 256><<<dim3(8, 64), 256, 0, stream>>>(
      yb, Wpb, bp, out, nullptr, nullptr, 4096, 1024, 1024, 1024, 1.0f);
}

// Round 10
// 176.516 us; speedup vs baseline: 1.5317x; 1.0166x over previous
//
#include <hip/hip_runtime.h>

typedef unsigned short ushort_t;
typedef __bf16 bf16x8 __attribute__((ext_vector_type(8)));
typedef float f32x4 __attribute__((ext_vector_type(4)));
typedef unsigned u32x4 __attribute__((ext_vector_type(4)));

// f32 -> bf16 bits, round-to-nearest-even (scalar path)
__device__ inline ushort_t f2bf(float f) {
  unsigned int u = __builtin_bit_cast(unsigned int, f);
  u += 0x7fff + ((u >> 16) & 1);
  return (ushort_t)(u >> 16);
}

// pack two f32 -> bf16x2 (RNE), b in high half — single HW instruction
__device__ inline unsigned pk_bf(float a, float b) {
  unsigned r;
  asm("v_cvt_pk_bf16_f32 %0, %1, %2" : "=v"(r) : "v"(a), "v"(b));
  return r;
}

// async global->LDS, 16B per lane; LDS dest = wave-uniform base + lane*16B
__device__ inline void async_ld16(const ushort_t* g, const ushort_t* l) {
  __builtin_amdgcn_global_load_lds(
      (const __attribute__((address_space(1))) void*)g,
      (__attribute__((address_space(3))) void*)l, 16, 0, 0);
}

// vmcnt(N) wait + workgroup barrier. IMM: 0x0F70|N (lgkm=15, exp=7 -> no wait)
template <int IMM>
__device__ inline void waitcnt_barrier() {
  asm volatile("" ::: "memory");
  __builtin_amdgcn_s_waitcnt(IMM);
  __builtin_amdgcn_s_barrier();
  asm volatile("" ::: "memory");
}

// one fused conversion kernel: x (1048576 f4) | Wa (786432 f4) | Wp (262144 f4)
__global__ void cvt_all(const float* __restrict__ x, const float* __restrict__ wa,
                        const float* __restrict__ wp, ushort_t* __restrict__ xb,
                        ushort_t* __restrict__ wab, ushort_t* __restrict__ wpb) {
  int i = blockIdx.x * 256 + threadIdx.x;
  const float* src;
  ushort_t* dst;
  int off;
  if (i < 1048576) { src = x; dst = xb; off = i; }
  else if (i < 1835008) { src = wa; dst = wab; off = i - 1048576; }
  else { src = wp; dst = wpb; off = i - 1835008; }
  float4 f = ((const float4*)src)[off];
  unsigned long long p = (unsigned long long)f2bf(f.x)
      | ((unsigned long long)f2bf(f.y) << 16)
      | ((unsigned long long)f2bf(f.z) << 32)
      | ((unsigned long long)f2bf(f.w) << 48);
  ((unsigned long long*)dst)[off] = p;
}

// C[m][n] = sum_k A[m][k]*B[n][k] + bias[n]; A:[M,K] bf16, B:[N,K] bf16.
// BK=32, TRIPLE-buffered LDS, depth-2 prefetch, manual vmcnt barriers.
template <int BM, int BN, int IM, int JN, int MODE, int TPB>
__global__ __launch_bounds__(TPB) void gemm_bt(
    const ushort_t* __restrict__ A, const ushort_t* __restrict__ B,
    const float* __restrict__ bias, float* __restrict__ Cf,
    ushort_t* __restrict__ Cb, ushort_t* __restrict__ vtb,
    int M, int N, int K, int ldc, float qscale) {
  constexpr int NWN = BN / (JN * 16);
  constexpr int NL = (BM + BN) * 32 / (TPB * 8);  // vmem loads/thread/stage
  constexpr int WIMM = 0x0F70 | NL;               // vmcnt(NL)
  __shared__ __align__(16) ushort_t As[3][BM * 32];
  __shared__ __align__(16) ushort_t Bs[3][BN * 32];
  const int tid = threadIdx.x;
  const int wave = tid >> 6, lane = tid & 63;
  const int quad = lane >> 4, l16 = lane & 15;
  const int wr = wave / NWN, wc = wave % NWN;
  const int wm = wr * IM * 16, wn = wc * JN * 16;
  const int m0 = blockIdx.y * BM, n0 = blockIdx.x * BN;
  const ushort_t* Ag = A + (size_t)m0 * K;
  const ushort_t* Bg = B + (size_t)n0 * K;
  const int slot = (quad ^ ((l16 >> 1) & 3)) * 8;
  f32x4 acc[IM][JN] = {};

  auto stage = [&](int kt, int bsel) {
    int k0 = kt * 32;
#pragma unroll
    for (int p = 0; p < BM * 4 / TPB; ++p) {
      int ci = p * TPB + tid;
      int row = ci >> 2, ch = (ci & 3) ^ ((ci >> 3) & 3);
      async_ld16(Ag + (size_t)row * K + k0 + ch * 8, As[bsel] + (p * TPB + wave * 64) * 8);
    }
#pragma unroll
    for (int p = 0; p < BN * 4 / TPB; ++p) {
      int ci = p * TPB + tid;
      int row = ci >> 2, ch = (ci & 3) ^ ((ci >> 3) & 3);
      async_ld16(Bg + (size_t)row * K + k0 + ch * 8, Bs[bsel] + (p * TPB + wave * 64) * 8);
    }
  };

  const int KT = K / 32;
  stage(0, 0);
  stage(1, 1);
  for (int kt = 0; kt < KT; ++kt) {
    waitcnt_barrier<WIMM>();  // stage(kt) landed; stage(kt+1) still in flight
    if (kt + 2 < KT) stage(kt + 2, (kt + 2) % 3);
    const ushort_t* Ac = As[kt % 3];
    const ushort_t* Bc = Bs[kt % 3];
    bf16x8 af[IM], bfr[JN];
#pragma unroll
    for (int i = 0; i < IM; ++i)
      af[i] = *(const bf16x8*)(Ac + (wm + i * 16 + l16) * 32 + slot);
#pragma unroll
    for (int j = 0; j < JN; ++j)
      bfr[j] = *(const bf16x8*)(Bc + (wn + j * 16 + l16) * 32 + slot);
#pragma unroll
    for (int i = 0; i < IM; ++i)
#pragma unroll
      for (int j = 0; j < JN; ++j)
        acc[i][j] = __builtin_amdgcn_mfma_f32_16x16x32_bf16(af[i], bfr[j], acc[i][j], 0, 0, 0);
  }

  if (MODE == 1 && n0 >= 2048) {
    // V third: write transposed packed to vtb[(b*16+h)*64+d][t]
#pragma unroll
    for (int j = 0; j < JN; ++j) {
      int col = n0 + wn + j * 16 + l16;
      int cv = col - 2048;
      float bv = bias[col];
      size_t rowbase = ((size_t)(cv >> 6)) * 64 + (cv & 63);  // (h*64+d) within batch
#pragma unroll
      for (int i = 0; i < IM; ++i) {
        int rowb = m0 + wm + i * 16 + quad * 4;
        int bb = rowb >> 11, t = rowb & 2047;
        uint2 pp;
        pp.x = pk_bf(acc[i][j][0] + bv, acc[i][j][1] + bv);
        pp.y = pk_bf(acc[i][j][2] + bv, acc[i][j][3] + bv);
        *(uint2*)(vtb + (((size_t)bb * 1024 + rowbase) * 2048 + t)) = pp;
      }
    }
    return;
  }
#pragma unroll
  for (int j = 0; j < JN; ++j) {
    int col = n0 + wn + j * 16 + l16;
    float bv = bias[col];
    float sc = (MODE == 1 && col < 1024) ? qscale : 1.0f;
#pragma unroll
    for (int i = 0; i < IM; ++i)
#pragma unroll
      for (int r = 0; r < 4; ++r) {
        int row = m0 + wm + i * 16 + quad * 4 + r;
        float v = (acc[i][j][r] + bv) * sc;
        if (MODE == 1)
          Cb[(size_t)row * ldc + col] = f2bf(v);
        else
          Cf[(size_t)row * ldc + col] = v;
      }
  }
}

// Transposed flash attention, causal, exp2 basis, static max.
// r20 CONSOLIDATION: flash9's work layout (r3, proven 43.6 µs) + flash12's
// ones-MFMA l-sum (proven r6/r9). The split-K+combine path (flash10..12)
// is NET NEGATIVE: flash12 42.3 + combine 4.5 = 46.8 > flash9's 43.6 —
// occupancy gained but the barrier-to-barrier chain still set iteration
// time, and combine was pure overhead. Reverted.
// Structure: two 64-key sub-tiles per super-iteration (independent
// S->softmax->pack chains; ONE barrier per 128 keys); LDS 2 super-buffers
// x 32KB = 64KB (2 blocks/CU); depth-1 prefetch, vmcnt(0) at the top
// barrier doubles as the WAR guard. s_setprio(1/0) around compute.
// Kappa-permuted K rows keep P in registers: kappa(jj,m)=16*(m>>2)+4jj+
// (m&3); PV B-frag = lane-local s[2ks],s[2ks+1] via v_cvt_pk_bf16_f32;
// V frag = contiguous 16B chunk ks+2quad. l[q] = sum_k P[k][q] via
// mfma(ones, pf, lacc) on the matrix pipe (A=ones -> layout-free; C/D
// col=lane&15 puts the sum in every reg of lane q) — deletes 16 VALU
// adds/tile + 2 epilogue shuffles.
// Balance: Q = (bh<16) ? 15-xx : xx so co-resident (i, i+256) sum = 34.
__global__ __launch_bounds__(512, 4) void flash15(
    const ushort_t* __restrict__ qk, const ushort_t* __restrict__ vt,
    ushort_t* __restrict__ y) {
  __shared__ __align__(16) ushort_t Kb[2][2][4096];
  __shared__ __align__(16) ushort_t Vb[2][2][4096];
  const int tid = threadIdx.x, wave = tid >> 6, lane = tid & 63;
  const int quad = lane >> 4, l16 = lane & 15;
  const int r7 = l16 & 7;
  // f(kappa(jj,l16)) = kappa bits {0,1,4} — jj-independent
  const int fK = (l16 & 3) | (((l16 >> 2) & 1) << 2);
  // kappa base row (elements): kappa(jj,l16) = 16*(l16>>2) + (l16&3) + 4*jj
  const int kbase = (16 * (l16 >> 2) + (l16 & 3)) * 64;
  const int xx = blockIdx.x, bh = blockIdx.y;
  const int Q = (bh < 16) ? (15 - xx) : xx;  // co-resident (i, i+256) sum = 34
  const int b = bh >> 4, h = bh & 15;
  const int bT = b * 2048;
  const int qw = Q * 128 + wave * 16;  // wave's q-frag rows (within batch)
  // all-ones A fragment (bf16 1.0 = 0x3F80) for the l row-sum MFMA
  u32x4 onesw;
  onesw[0] = 0x3F803F80u; onesw[1] = 0x3F803F80u;
  onesw[2] = 0x3F803F80u; onesw[3] = 0x3F803F80u;
  const bf16x8 ones = __builtin_bit_cast(bf16x8, onesw);

  // Q B-fragment direct from global: rows qw+l16
  bf16x8 qf[2];
  {
    const ushort_t* qrow = qk + (size_t)(bT + qw + l16) * 2048 + h * 64 + quad * 8;
    qf[0] = *(const bf16x8*)(qrow);
    qf[1] = *(const bf16x8*)(qrow + 32);
  }

  // stage one 64-key sub-tile kt into (bsel, u)
  auto stage1 = [&](int kt, int bsel, int u) {
    int k0 = kt * 64;
    int row = tid >> 3;
    int chk = (tid & 7) ^ ((row & 3) | (((row >> 4) & 1) << 2));  // f(key)
    int chv = (tid & 7) ^ (row & 7);                              // d&7
    async_ld16(qk + (size_t)(bT + k0 + row) * 2048 + 1024 + h * 64 + chk * 8,
               Kb[bsel][u] + wave * 512);
    async_ld16(vt + (size_t)(bh * 64 + row) * 2048 + k0 + chv * 8,
               Vb[bsel][u] + wave * 512);
  };
  auto stageS = [&](int s, int bsel) { stage1(2 * s, bsel, 0); stage1(2 * s + 1, bsel, 1); };

  f32x4 o[4] = {};
  f32x4 lacc = {};
  const int NS = Q + 1;  // super-iterations (2 K-tiles each); KT = 2*NS

  stageS(0, 0);
  for (int s = 0; s < NS; ++s) {
    const int cur = s & 1;
    // stage(s) landed (issued one full body ago except s=0); all waves done
    // reading buffer cur^1 -> safe to re-stage it.
    waitcnt_barrier<0x0F70>();
    if (s + 1 < NS) stageS(s + 1, cur ^ 1);
    __builtin_amdgcn_s_setprio(1);
#pragma unroll
    for (int u = 0; u < 2; ++u) {
      const ushort_t* Kc = Kb[cur][u];
      const ushort_t* Vc = Vb[cur][u];
      // K fragments in kappa row order: row kappa(jj,l16), d-chunk ks*4+quad
      bf16x8 kf[4][2];
#pragma unroll
      for (int jj = 0; jj < 4; ++jj)
#pragma unroll
        for (int ks = 0; ks < 2; ++ks)
          kf[jj][ks] = *(const bf16x8*)(Kc + kbase + jj * 256 + (((ks * 4 + quad) ^ fK) * 8));
      // S^T: 8 MFMAs, 4 independent chains of 2
      f32x4 sr[4] = {};
#pragma unroll
      for (int ks = 0; ks < 2; ++ks)
#pragma unroll
        for (int jj = 0; jj < 4; ++jj)
          sr[jj] = __builtin_amdgcn_mfma_f32_16x16x32_bf16(kf[jj][ks], qf[ks], sr[jj], 0, 0, 0);
      if (s == NS - 1) {  // diagonal region: elementwise causal mask (kappa keys)
        int qloc = qw + l16;
        int kt0 = (2 * s + u) * 64;
#pragma unroll
        for (int jj = 0; jj < 4; ++jj)
#pragma unroll
          for (int r = 0; r < 4; ++r)
            if (kt0 + quad * 16 + jj * 4 + r > qloc) sr[jj][r] = -1e30f;
      }
      // static-max softmax, fully in-register
#pragma unroll
      for (int jj = 0; jj < 4; ++jj)
#pragma unroll
        for (int r = 0; r < 4; ++r)
          sr[jj][r] = exp2f(sr[jj][r]);
      // P^T B-frags are lane-local under kappa: keys 8ks+16quad+0..7
      bf16x8 pf[2];
#pragma unroll
      for (int ks = 0; ks < 2; ++ks) {
        u32x4 wd;
        wd[0] = pk_bf(sr[2 * ks][0], sr[2 * ks][1]);
        wd[1] = pk_bf(sr[2 * ks][2], sr[2 * ks][3]);
        wd[2] = pk_bf(sr[2 * ks + 1][0], sr[2 * ks + 1][1]);
        wd[3] = pk_bf(sr[2 * ks + 1][2], sr[2 * ks + 1][3]);
        pf[ks] = __builtin_bit_cast(bf16x8, wd);
      }
      // l row-sum on the matrix pipe: lacc[q] += sum_k P[k][q]
      lacc = __builtin_amdgcn_mfma_f32_16x16x32_bf16(ones, pf[0], lacc, 0, 0, 0);
      lacc = __builtin_amdgcn_mfma_f32_16x16x32_bf16(ones, pf[1], lacc, 0, 0, 0);
      // O^T += V^T * P^T; V frag = keys 8ks+16quad+0..7 (chunk ks+2quad)
#pragma unroll
      for (int ks = 0; ks < 2; ++ks)
#pragma unroll
        for (int jj = 0; jj < 4; ++jj) {
          bf16x8 vf = *(const bf16x8*)(Vc + (jj * 16 + l16) * 64 + (((ks + 2 * quad) ^ r7) * 8));
          o[jj] = __builtin_amdgcn_mfma_f32_16x16x32_bf16(vf, pf[ks], o[jj], 0, 0, 0);
        }
    }
    __builtin_amdgcn_s_setprio(0);
  }

  // epilogue: l already fully reduced (every reg/quad of lane q holds the sum)
  {
    float inv = 1.f / lacc[0];
    size_t row = (size_t)(bT + qw + l16);
#pragma unroll
    for (int jj = 0; jj < 4; ++jj) {
      uint2 pp;
      pp.x = pk_bf(o[jj][0] * inv, o[jj][1] * inv);
      pp.y = pk_bf(o[jj][2] * inv, o[jj][3] * inv);
      *(uint2*)(y + row * 1024 + h * 64 + jj * 16 + quad * 4) = pp;
    }
  }
}

extern "C" void kernel_launch(void* const* d_in, const int* in_sizes, int n_in,
                              void* d_out, int out_size, void* d_ws, size_t ws_size,
                              hipStream_t stream) {
  const float* x  = (const float*)d_in[0];
  const float* Wa = (const float*)d_in[1];
  const float* ba = (const float*)d_in[2];
  const float* Wp = (const float*)d_in[3];
  const float* bp = (const float*)d_in[4];
  float* out = (float*)d_out;
  char* ws = (char*)d_ws;
  // ws: xb 8.39M | Wab 6.29M | Wpb 2.10M | qk 16.78M | yb 8.39M | vt 8.39M
  ushort_t* xb  = (ushort_t*)(ws);
  ushort_t* Wab = (ushort_t*)(ws + 8388608);
  ushort_t* Wpb = (ushort_t*)(ws + 14680064);
  ushort_t* qkb = (ushort_t*)(ws + 16777216);
  ushort_t* yb  = (ushort_t*)(ws + 33554432);
  ushort_t* vtb = (ushort_t*)(ws + 41943040);

  cvt_all<<<8192, 256, 0, stream>>>(x, Wa, Wp, xb, Wab, Wpb);
  // qkv = x @ W_attn^T + b_attn; Q scaled by 0.125*log2(e); V written transposed
  gemm_bt<128, 128, 4, 2, 1, 512><<<dim3(24, 32), 512, 0, stream>>>(
      xb, Wab, ba, nullptr, qkb, vtb, 4096, 3072, 1024, 2048, 0.18033688011112042f);
  // flash attention -> yb [4096,1024] bf16 (512 blocks, q=128/block, 8 waves,
  // 2 K-tiles per barrier, snake-balanced, direct final writes)
  flash15<<<dim3(16, 32), 512, 0, stream>>>(qkb, vtb, yb);
  // out = yb @ W_proj^T + b_proj  [4096,1024] f32 — 64x128 tile, 512 blocks
  gemm_bt<64, 128, 4, 2, 0, 256><<<dim3(8, 64), 256, 0, stream>>>(
      yb, Wpb, bp, out, nullptr, nullptr, 4096, 1024, 1024, 1024, 1.0f);
}